// Round 4
// baseline (487.044 us; speedup 1.0000x reference)
//
#include <hip/hip_runtime.h>

// EUNN: 256 layers; each layer = rotation on even pairs (2i,2i+1), then
// rotation on odd pairs (2i+1,2i+2 mod H).
// Pair math: y0 = e^{i*phi} (ct*u - st*v); y1 = st*u + ct*v.

#define H_DIM 1024
#define C2 256
#define RPW 2   // batch rows per wave

// coef layout: [c][phase][j][lane] as float4 (ct, st, cp, sp), pair i = 8*lane + j
// -> flat float4 index: ((c*2 + phase)*8 + j)*64 + lane,  4 MB total.

__global__ __launch_bounds__(256) void eunn_coef_kernel(
    const float* __restrict__ phi0, const float* __restrict__ theta0,
    const float* __restrict__ phi1, const float* __restrict__ theta1,
    float4* __restrict__ coef) {
    int t = blockIdx.x * 256 + threadIdx.x;     // [0, 256*2*512)
    int i = t & 511;                            // pair index
    int p = (t >> 9) & 1;                       // phase (0: even pairs, 1: odd pairs)
    int c = t >> 10;                            // layer
    const float* phi   = p ? phi1   : phi0;
    const float* theta = p ? theta1 : theta0;
    float ph = phi[i * C2 + c];
    float th = theta[i * C2 + c];
    float sp, cp, st, ct;
    __sincosf(ph, &sp, &cp);
    __sincosf(th, &st, &ct);
    int j = i & 7;
    int l = i >> 3;
    coef[(((c * 2 + p) * 8) + j) * 64 + l] = make_float4(ct, st, cp, sp);
}

__device__ __forceinline__ void rot_pair(const float4 q,
                                         float& ur, float& ui,
                                         float& wr, float& wi) {
    // q = (ct, st, cp, sp)
    float ar = fmaf(-q.y, wr, q.x * ur);   // ct*u - st*v (real part)
    float ai = fmaf(-q.y, wi, q.x * ui);
    float br = fmaf( q.x, wr, q.y * ur);   // st*u + ct*v
    float bi = fmaf( q.x, wi, q.y * ui);
    ur = fmaf(-q.w, ai, q.z * ar);         // e^{i phi} * a
    ui = fmaf( q.w, ar, q.z * ai);
    wr = br;
    wi = bi;
}

// Session ledger:
//  R0 (baseline structure): RPW=2, direct L2, load-use ~0 (VGPR 76). 375us,
//      VALUBusy 62%. ~14 exposed L2/L1 stalls per layer.
//  R1: 4x float4[8] reg prefetch -> demand ~200 VGPR vs 128 cap -> scratch
//      spill (WRITE_SIZE 33MB->1.66GB), 902us. Bounded prefetch only.
//  R2: LDS staging at RPW=2 -> LDS pipe oversubscribed + 2 barriers/layer,
//      424us, VALUBusy 54%. Dead end.
//  R3: RPW=4 + bulk 16-load batches + sched_barrier walls at 1 wave/SIMD ->
//      VGPR 160 (pipeline collapsed by allocator), zero cross-wave cover,
//      436us, VALUBusy 56%. Bulk batches + hard fences don't survive regalloc.
//  R4 (this): exact R0 structure + rolling 4x4-batch prefetch. PIN4 = empty
//      asm "+v" on a batch -> counted waitcnt at section top, consumers can't
//      hoist. MEMFENCE = empty asm "memory" clobber right after issuing the
//      next batch -> loads can't sink into the compute section (scheduler
//      can't re-collapse load-use distance); pure FMAs still move freely.
//      Load->use distance = one compute section (~350-430cy) > L2 latency.
//      Bounded: <=8 float4 in flight -> ~120 VGPR, no spill possible.

#define ROT2(q, e0, e1)                                                  \
    do {                                                                 \
        _Pragma("unroll")                                                \
        for (int r = 0; r < RPW; ++r)                                    \
            rot_pair(q, vr[r][e0], vi[r][e0], vr[r][e1], vi[r][e1]);     \
    } while (0)

#define PIN4(a, b, c, d)                                                 \
    asm volatile(""                                                      \
        : "+v"(a.x), "+v"(a.y), "+v"(a.z), "+v"(a.w),                    \
          "+v"(b.x), "+v"(b.y), "+v"(b.z), "+v"(b.w),                    \
          "+v"(c.x), "+v"(c.y), "+v"(c.z), "+v"(c.w),                    \
          "+v"(d.x), "+v"(d.y), "+v"(d.z), "+v"(d.w))

#define MEMFENCE asm volatile("" ::: "memory")

__global__ __launch_bounds__(256, 2) void eunn_main_kernel(
    const float* __restrict__ x,
    const float4* __restrict__ coef,
    float* __restrict__ out) {
    const int lane = threadIdx.x & 63;
    const int wave = threadIdx.x >> 6;
    const int row0 = (blockIdx.x * 4 + wave) * RPW;
    const int lnext = (lane + 1) & 63;
    const int lprev = (lane + 63) & 63;

    // lane owns complex elements [16*lane, 16*lane+16) of each of its RPW rows
    float vr[RPW][16], vi[RPW][16];

#pragma unroll
    for (int r = 0; r < RPW; ++r) {
        const float4* src = (const float4*)(x + (size_t)(row0 + r) * (H_DIM * 2)) + lane * 8;
#pragma unroll
        for (int m = 0; m < 8; ++m) {
            float4 f = src[m];
            vr[r][2 * m]     = f.x; vi[r][2 * m]     = f.y;
            vr[r][2 * m + 1] = f.z; vi[r][2 * m + 1] = f.w;
        }
    }

    const float4* cl = coef + lane;   // lane-offset base

    // prologue: batch0 of layer 0 in flight {a0, a7, qq, a1}
    float4 pA0 = cl[0 * 64], pA7 = cl[7 * 64], pQQ = cl[15 * 64], pA1 = cl[1 * 64];

#pragma unroll 1
    for (int c = 0; c < C2; ++c) {
        const float4* cb = cl + (size_t)c * 1024;
        const float4* cn = cl + (size_t)((c + 1) & (C2 - 1)) * 1024;  // last iter: dummy

        // ---- section 0: consume batch0 {a0,a7,qq,a1}; issue batch1 {a2..a5}
        PIN4(pA0, pA7, pQQ, pA1);
        float4 pA2 = cb[2 * 64], pA3 = cb[3 * 64], pA4 = cb[4 * 64], pA5 = cb[5 * 64];
        MEMFENCE;
        float4 qq = pQQ;                       // survives batch0 reuse in sec.3
        float qpx = __shfl(qq.x, lprev);       // prev lane's ct'
        float qpy = __shfl(qq.y, lprev);       // prev lane's st'
        ROT2(pA0, 0, 1);
        ROT2(pA7, 14, 15);
        float nbr[RPW], nbi[RPW], pbr[RPW], pbi[RPW];
#pragma unroll
        for (int r = 0; r < RPW; ++r) {
            nbr[r] = __shfl(vr[r][0],  lnext);   // next lane's post-A elem0
            nbi[r] = __shfl(vi[r][0],  lnext);
            pbr[r] = __shfl(vr[r][15], lprev);   // prev lane's post-A elem15
            pbi[r] = __shfl(vi[r][15], lprev);
        }
        ROT2(pA1, 2, 3);

        // ---- section 1: consume batch1; issue batch2 {a6,b0,b1,b2}
        PIN4(pA2, pA3, pA4, pA5);
        float4 pA6 = cb[6 * 64], pB0 = cb[8 * 64], pB1 = cb[9 * 64], pB2 = cb[10 * 64];
        MEMFENCE;
        ROT2(pA2, 4, 5);
        ROT2(pA3, 6, 7);
        ROT2(pA4, 8, 9);
        ROT2(pA5, 10, 11);

        // ---- section 2: consume batch2; issue batch3 {b3..b6}
        PIN4(pA6, pB0, pB1, pB2);
        float4 pB3 = cb[11 * 64], pB4 = cb[12 * 64], pB5 = cb[13 * 64], pB6 = cb[14 * 64];
        MEMFENCE;
        ROT2(pA6, 12, 13);
        ROT2(pB0, 1, 2);
        ROT2(pB1, 3, 4);
        ROT2(pB2, 5, 6);

        // ---- section 3: consume batch3; issue next layer's batch0
        PIN4(pB3, pB4, pB5, pB6);
        pA0 = cn[0 * 64]; pA7 = cn[7 * 64]; pQQ = cn[15 * 64]; pA1 = cn[1 * 64];
        MEMFENCE;
        ROT2(pB3, 7, 8);
        ROT2(pB4, 9, 10);
        ROT2(pB5, 11, 12);
        ROT2(pB6, 13, 14);

        // phase B boundary pair (my elem15, next lane's elem0)
#pragma unroll
        for (int r = 0; r < RPW; ++r) {
            // new elem15 = e^{i phi}(ct*e15 - st*next_e0)
            float ar = fmaf(-qq.y, nbr[r], qq.x * vr[r][15]);
            float ai = fmaf(-qq.y, nbi[r], qq.x * vi[r][15]);
            vr[r][15] = fmaf(-qq.w, ai, qq.z * ar);
            vi[r][15] = fmaf( qq.w, ar, qq.z * ai);
            // new elem0 = st'*prev_e15 + ct'*e0
            float b0r = fmaf(qpx, vr[r][0], qpy * pbr[r]);
            float b0i = fmaf(qpx, vi[r][0], qpy * pbi[r]);
            vr[r][0] = b0r; vi[r][0] = b0i;
        }
    }

#pragma unroll
    for (int r = 0; r < RPW; ++r) {
        float4* dst = (float4*)(out + (size_t)(row0 + r) * (H_DIM * 2)) + lane * 8;
#pragma unroll
        for (int m = 0; m < 8; ++m) {
            dst[m] = make_float4(vr[r][2 * m],     vi[r][2 * m],
                                 vr[r][2 * m + 1], vi[r][2 * m + 1]);
        }
    }
}

extern "C" void kernel_launch(void* const* d_in, const int* in_sizes, int n_in,
                              void* d_out, int out_size, void* d_ws, size_t ws_size,
                              hipStream_t stream) {
    const float* x      = (const float*)d_in[0];
    const float* phi0   = (const float*)d_in[1];
    const float* theta0 = (const float*)d_in[2];
    const float* phi1   = (const float*)d_in[3];
    const float* theta1 = (const float*)d_in[4];
    float* out = (float*)d_out;
    float4* coef = (float4*)d_ws;   // 256*1024 float4 = 4 MB

    // coefficients: 256 layers * 2 phases * 512 pairs = 262144 threads
    hipLaunchKernelGGL(eunn_coef_kernel, dim3(1024), dim3(256), 0, stream,
                       phi0, theta0, phi1, theta1, coef);

    // main: 4096 rows / (4 waves/block * RPW rows/wave) = 512 blocks
    hipLaunchKernelGGL(eunn_main_kernel, dim3(512), dim3(256), 0, stream,
                       x, coef, out);
}

// Round 6
// 465.888 us; speedup vs baseline: 1.0454x; 1.0454x over previous
//
#include <hip/hip_runtime.h>

// EUNN: 256 layers; each layer = rotation on even pairs (2i,2i+1), then
// rotation on odd pairs (2i+1,2i+2 mod H).
// Pair math: y0 = e^{i*phi} (ct*u - st*v); y1 = st*u + ct*v.
//
// Session ledger:
//  R0: RPW=2 full-row waves, direct L2, compiler schedule. 375us, busy 62%.
//      Per-CU/layer: VMEM ~2048cy (8 waves x 16 x 1KB loads) > VALU ~1700cy
//      -> memory co-critical; latency exposed.
//  R1: 4x float4[8] reg prefetch -> spill (WRITE 33MB->1.66GB), 902us.
//  R2: LDS-staged coefs -> LDS pipe oversubscribed + 2 vmcnt-draining
//      barriers/layer, 424us.
//  R3: RPW=4 @1 wave/SIMD -> zero co-wave latency cover, 436us.
//  R4: PIN4/MEMFENCE micro-scheduling -> +35us instructions, collapse anyway,
//      452us. Lesson: fix the traffic, not the schedule.
//  R5: wave-slice structure -- FAILED on a launch bug: coef kernel ran 512
//      blocks (131072 threads) but the table is 262144 entries; layers
//      128-255 read garbage (absmax 5.6). Structure audited OK.
//  R6 (this): R5 with the coef grid fixed to 1024 blocks. Slice H across
//      2 waves/block (wave = 512-elem slice x 4 rows). Coef/wave/layer:
//      16KB -> 8KB -> per-CU VMEM ~1024cy < VALU. Full-layer coef ping-pong
//      in registers (64 VGPR), load->use distance = one layer. Phase-B wave
//      boundary via 5-float4 LDS exchange + ONE raw s_barrier/layer (lgkmcnt
//      drain only, NO vmcnt drain -> prefetch stays in flight).
//      1024 blocks x 128 thr = 8 waves/CU.

#define H_DIM 1024
#define C2 256

// coef layout: [c][w][p][k][lane] float4(ct,st,cp,sp);
// flat idx = c*1024 + w*512 + p*256 + k*64 + lane.  262144 float4 = 4 MB.
// (c,w,p,k,lane) covers phase-p pair i = 256*w + 4*lane + k.

__global__ __launch_bounds__(256) void eunn_coef_kernel(
    const float* __restrict__ phi0, const float* __restrict__ theta0,
    const float* __restrict__ phi1, const float* __restrict__ theta1,
    float4* __restrict__ coef) {
    int t = blockIdx.x * 256 + threadIdx.x;     // [0, 262144)
    int l = t & 63;
    int k = (t >> 6) & 3;
    int p = (t >> 8) & 1;
    int w = (t >> 9) & 1;
    int c = t >> 10;                            // [0, 256)
    int i = 256 * w + 4 * l + k;                // pair index in [0,512)
    const float* phi   = p ? phi1   : phi0;
    const float* theta = p ? theta1 : theta0;
    float ph = phi[i * C2 + c];
    float th = theta[i * C2 + c];
    float sp, cp, st, ct;
    __sincosf(ph, &sp, &cp);
    __sincosf(th, &st, &ct);
    coef[t] = make_float4(ct, st, cp, sp);      // perfectly coalesced write
}

__device__ __forceinline__ void rot_pair(const float4 q,
                                         float& ur, float& ui,
                                         float& wr, float& wi) {
    // q = (ct, st, cp, sp)
    float ar = fmaf(-q.y, wr, q.x * ur);   // ct*u - st*v (real part)
    float ai = fmaf(-q.y, wi, q.x * ui);
    float br = fmaf( q.x, wr, q.y * ur);   // st*u + ct*v
    float bi = fmaf( q.x, wi, q.y * ui);
    ur = fmaf(-q.w, ai, q.z * ar);         // e^{i phi} * a
    ui = fmaf( q.w, ar, q.z * ai);
    wr = br;
    wi = bi;
}

__global__ __launch_bounds__(128, 2) void eunn_main_kernel(
    const float* __restrict__ x,
    const float4* __restrict__ coef,
    float* __restrict__ out) {
    const int lane = threadIdx.x & 63;
    const int w    = threadIdx.x >> 6;          // wave slice: elements [512w, 512w+512)
    const int row0 = blockIdx.x * 4;
    const int lnext = (lane + 1) & 63;
    const int lprev = (lane + 63) & 63;

    // exchange: [parity][wave][0..1]=lane0 post-A elem0 rows0-3,
    //                        [2..3]=lane63 post-A elem7 rows0-3, [4]=qq.xy
    __shared__ float4 ex[2][2][5];

    // lane owns elements [512w + 8*lane, +8) of rows row0..row0+3
    float vr[4][8], vi[4][8];

#pragma unroll
    for (int r = 0; r < 4; ++r) {
        const float4* src = (const float4*)(x + (size_t)(row0 + r) * (H_DIM * 2))
                            + (w * 256 + lane * 4);
#pragma unroll
        for (int k = 0; k < 4; ++k) {
            float4 f = src[k];
            vr[r][2 * k]     = f.x; vi[r][2 * k]     = f.y;
            vr[r][2 * k + 1] = f.z; vi[r][2 * k + 1] = f.w;
        }
    }

    const float4* cl = coef + (w * 512 + lane);   // + c*1024 + p*256 + k*64

    // Full-layer coef ping-pong: CA/CB = current layer, NA/NB = prefetch.
    float4 CA[4], CB[4], NA[4], NB[4];
#pragma unroll
    for (int k = 0; k < 4; ++k) {
        CA[k] = cl[k * 64];
        CB[k] = cl[256 + k * 64];
    }

#define LAYER(CA_, CB_, NA_, NB_, cnext, par)                                      \
    do {                                                                           \
        /* prefetch next layer's 8 coef float4 (consumed next LAYER) */            \
        const float4* cn_ = cl + (size_t)(cnext) * 1024;                           \
        _Pragma("unroll")                                                          \
        for (int k = 0; k < 4; ++k) {                                              \
            NA_[k] = cn_[k * 64];                                                  \
            NB_[k] = cn_[256 + k * 64];                                            \
        }                                                                          \
        float4 qq = CB_[3];                                                        \
        float qpx = __shfl(qq.x, lprev);     /* prev ring lane's ct' */            \
        float qpy = __shfl(qq.y, lprev);     /* prev ring lane's st' */            \
        /* phase A: pairs (2k, 2k+1), lane-local */                                \
        _Pragma("unroll")                                                          \
        for (int k = 0; k < 4; ++k)                                                \
            _Pragma("unroll")                                                      \
            for (int r = 0; r < 4; ++r)                                            \
                rot_pair(CA_[k], vr[r][2 * k],     vi[r][2 * k],                   \
                                 vr[r][2 * k + 1], vi[r][2 * k + 1]);              \
        /* post-A neighbors: intra-wave via shuffle; ring edges via LDS */         \
        float nbr[4], nbi[4], pbr[4], pbi[4];                                      \
        _Pragma("unroll")                                                          \
        for (int r = 0; r < 4; ++r) {                                              \
            nbr[r] = __shfl(vr[r][0], lnext);                                      \
            nbi[r] = __shfl(vi[r][0], lnext);                                      \
            pbr[r] = __shfl(vr[r][7], lprev);                                      \
            pbi[r] = __shfl(vi[r][7], lprev);                                      \
        }                                                                          \
        if (lane == 0) {                                                           \
            ex[par][w][0] = make_float4(vr[0][0], vi[0][0], vr[1][0], vi[1][0]);   \
            ex[par][w][1] = make_float4(vr[2][0], vi[2][0], vr[3][0], vi[3][0]);   \
        } else if (lane == 63) {                                                   \
            ex[par][w][2] = make_float4(vr[0][7], vi[0][7], vr[1][7], vi[1][7]);   \
            ex[par][w][3] = make_float4(vr[2][7], vi[2][7], vr[3][7], vi[3][7]);   \
            ex[par][w][4] = make_float4(qq.x, qq.y, qq.x, qq.y);                   \
        }                                                                          \
        /* raw barrier: lgkm drain only — prefetch (vmcnt) stays in flight */      \
        asm volatile("" ::: "memory");                                             \
        asm volatile("s_waitcnt lgkmcnt(0)" ::: "memory");                         \
        __builtin_amdgcn_s_barrier();                                              \
        asm volatile("" ::: "memory");                                             \
        {                                                                          \
            float4 e0a = ex[par][w ^ 1][0], e0b = ex[par][w ^ 1][1];               \
            float4 e7a = ex[par][w ^ 1][2], e7b = ex[par][w ^ 1][3];               \
            float4 qpo = ex[par][w ^ 1][4];                                        \
            if (lane == 63) {                                                      \
                nbr[0] = e0a.x; nbi[0] = e0a.y; nbr[1] = e0a.z; nbi[1] = e0a.w;    \
                nbr[2] = e0b.x; nbi[2] = e0b.y; nbr[3] = e0b.z; nbi[3] = e0b.w;    \
            }                                                                      \
            if (lane == 0) {                                                       \
                pbr[0] = e7a.x; pbi[0] = e7a.y; pbr[1] = e7a.z; pbi[1] = e7a.w;    \
                pbr[2] = e7b.x; pbi[2] = e7b.y; pbr[3] = e7b.z; pbi[3] = e7b.w;    \
                qpx = qpo.x; qpy = qpo.y;                                          \
            }                                                                      \
        }                                                                          \
        /* phase B internal: pairs (2k+1, 2k+2), k=0..2 */                         \
        _Pragma("unroll")                                                          \
        for (int k = 0; k < 3; ++k)                                                \
            _Pragma("unroll")                                                      \
            for (int r = 0; r < 4; ++r)                                            \
                rot_pair(CB_[k], vr[r][2 * k + 1], vi[r][2 * k + 1],               \
                                 vr[r][2 * k + 2], vi[r][2 * k + 2]);              \
        /* phase B boundary: (my elem7, ring-next elem0) */                        \
        _Pragma("unroll")                                                          \
        for (int r = 0; r < 4; ++r) {                                              \
            float ar = fmaf(-qq.y, nbr[r], qq.x * vr[r][7]);                       \
            float ai = fmaf(-qq.y, nbi[r], qq.x * vi[r][7]);                       \
            vr[r][7] = fmaf(-qq.w, ai, qq.z * ar);                                 \
            vi[r][7] = fmaf( qq.w, ar, qq.z * ai);                                 \
            float b0r = fmaf(qpx, vr[r][0], qpy * pbr[r]);                         \
            float b0i = fmaf(qpx, vi[r][0], qpy * pbi[r]);                         \
            vr[r][0] = b0r; vi[r][0] = b0i;                                        \
        }                                                                          \
    } while (0)

#pragma unroll 1
    for (int c = 0; c < C2; c += 2) {
        LAYER(CA, CB, NA, NB, c + 1, 0);
        LAYER(NA, NB, CA, CB, (c + 2) & (C2 - 1), 1);   // last: dummy wrap to 0
    }
#undef LAYER

#pragma unroll
    for (int r = 0; r < 4; ++r) {
        float4* dst = (float4*)(out + (size_t)(row0 + r) * (H_DIM * 2))
                      + (w * 256 + lane * 4);
#pragma unroll
        for (int k = 0; k < 4; ++k) {
            dst[k] = make_float4(vr[r][2 * k],     vi[r][2 * k],
                                 vr[r][2 * k + 1], vi[r][2 * k + 1]);
        }
    }
}

extern "C" void kernel_launch(void* const* d_in, const int* in_sizes, int n_in,
                              void* d_out, int out_size, void* d_ws, size_t ws_size,
                              hipStream_t stream) {
    const float* x      = (const float*)d_in[0];
    const float* phi0   = (const float*)d_in[1];
    const float* theta0 = (const float*)d_in[2];
    const float* phi1   = (const float*)d_in[3];
    const float* theta1 = (const float*)d_in[4];
    float* out = (float*)d_out;
    float4* coef = (float4*)d_ws;   // 262144 float4 = 4 MB

    // coefficients: 256 layers * 1024 float4/layer = 262144 threads
    // (R5 bug: this was 512 blocks -> layers 128-255 uninitialized)
    hipLaunchKernelGGL(eunn_coef_kernel, dim3(1024), dim3(256), 0, stream,
                       phi0, theta0, phi1, theta1, coef);

    // main: 4096 rows / 4 rows-per-block = 1024 blocks of 128 threads
    hipLaunchKernelGGL(eunn_main_kernel, dim3(1024), dim3(128), 0, stream,
                       x, coef, out);
}